// Round 2
// baseline (249.367 us; speedup 1.0000x reference)
//
#include <hip/hip_runtime.h>

// Problem constants (from reference):
//   B=16, LX=2048, LR=1024, D=768, T = LX+LR+3 = 3075
// out[b,t,:] =
//   t==0                       -> CLS
//   1 <= t <= lx[b]            -> X[b, t-1, :]
//   t == lx[b]+1               -> RING
//   lx[b]+2 <= t < lx[b]+2+lr  -> Xr[b, t-lx[b]-2, :]
//   t == lx[b]+lr[b]+2         -> END
//   else                       -> 0
//
// Dtype contract: reference declares float32 everywhere -> fp32 buffers
// (the bf16-ish test threshold is value-lowering, not storage dtype).
// One thread per 16B float4 chunk; 768 % 4 == 0 so a chunk never crosses
// a (b,t) row boundary. Coalesced float4 load + store.

constexpr int B_  = 16;
constexpr int LX_ = 2048;
constexpr int LR_ = 1024;
constexpr int D_  = 768;
constexpr int T_  = LX_ + LR_ + 3;      // 3075
constexpr int VEC  = 4;                 // floats per thread (16 bytes)
constexpr int VROW = D_ / VEC;          // 192 vectors per row
constexpr int NVEC = B_ * T_ * VROW;    // 9,446,400 vector units (fits int)

__global__ __launch_bounds__(256)
void assemble_kernel(const float* __restrict__ X,
                     const float* __restrict__ Xr,
                     const float* __restrict__ CLS,
                     const float* __restrict__ RING,
                     const float* __restrict__ END,
                     const int* __restrict__ lx,
                     const int* __restrict__ lr,
                     float* __restrict__ out)
{
    int v = blockIdx.x * blockDim.x + threadIdx.x;
    if (v >= NVEC) return;

    int row = v / VROW;            // b*T + t   (magic-mul div by 192)
    int dv  = v - row * VROW;      // vector index within row
    int b   = row / T_;            // magic-mul div by 3075
    int t   = row - b * T_;

    const int lxb = lx[b];
    const int lrb = lr[b];
    const int doff = dv * VEC;

    const float* src = nullptr;
    if (t == 0) {
        src = CLS + doff;
    } else if (t <= lxb) {
        src = X + ((size_t)(b * LX_ + (t - 1)) * D_ + doff);
    } else if (t == lxb + 1) {
        src = RING + doff;
    } else if (t < lxb + 2 + lrb) {
        src = Xr + ((size_t)(b * LR_ + (t - lxb - 2)) * D_ + doff);
    } else if (t == lxb + lrb + 2) {
        src = END + doff;
    }

    float4 val = make_float4(0.f, 0.f, 0.f, 0.f);
    if (src) {
        val = *reinterpret_cast<const float4*>(src);
    }
    *reinterpret_cast<float4*>(out + (size_t)row * D_ + doff) = val;
}

extern "C" void kernel_launch(void* const* d_in, const int* in_sizes, int n_in,
                              void* d_out, int out_size, void* d_ws, size_t ws_size,
                              hipStream_t stream)
{
    const float* X    = (const float*)d_in[0];
    const float* Xr   = (const float*)d_in[1];
    const float* CLS  = (const float*)d_in[2];
    const float* RING = (const float*)d_in[3];
    const float* END  = (const float*)d_in[4];
    const int* lx = (const int*)d_in[5];
    const int* lr = (const int*)d_in[6];
    float* out = (float*)d_out;

    const int threads = 256;
    const int blocks  = (NVEC + threads - 1) / threads;
    hipLaunchKernelGGL(assemble_kernel, dim3(blocks), dim3(threads), 0, stream,
                       X, Xr, CLS, RING, END, lx, lr, out);
}

// Round 4
// 242.079 us; speedup vs baseline: 1.0301x; 1.0301x over previous
//
#include <hip/hip_runtime.h>

// Problem constants (from reference):
//   B=16, LX=2048, LR=1024, D=768, T = LX+LR+3 = 3075
// out[b,t,:] =
//   t==0                       -> CLS
//   1 <= t <= lx[b]            -> X[b, t-1, :]
//   t == lx[b]+1               -> RING
//   lx[b]+2 <= t < lx[b]+2+lr  -> Xr[b, t-lx[b]-2, :]
//   t == lx[b]+lr[b]+2         -> END
//   else                       -> 0
//
// R4: one (b,t) row per 192-thread block (3 waves). Branch + lx/lr loads are
// block-uniform (scalar path, zero divergence); each thread moves one float4.
// Non-temporal load/store on the streaming tensors (X, Xr, out); CLS/RING/END
// stay cached (reused by every block). Nontemporal builtins need a Clang
// ext_vector_type, not HIP_vector_type -> vfloat4 alias.

constexpr int B_  = 16;
constexpr int LX_ = 2048;
constexpr int LR_ = 1024;
constexpr int D_  = 768;
constexpr int T_  = LX_ + LR_ + 3;      // 3075
constexpr int NROW = B_ * T_;           // 49200 rows

typedef float vfloat4 __attribute__((ext_vector_type(4)));

__global__ __launch_bounds__(192)
void assemble_row_kernel(const float* __restrict__ X,
                         const float* __restrict__ Xr,
                         const float* __restrict__ CLS,
                         const float* __restrict__ RING,
                         const float* __restrict__ END,
                         const int* __restrict__ lx,
                         const int* __restrict__ lr,
                         float* __restrict__ out)
{
    const unsigned row = blockIdx.x;          // b*T + t, uniform
    const unsigned b   = row / (unsigned)T_;  // magic-mul, scalar
    const int      t   = (int)(row - b * (unsigned)T_);

    const int lxb = lx[b];                    // uniform -> s_load
    const int lrb = lr[b];
    const int doff = threadIdx.x * 4;         // float offset within row

    vfloat4 val = (vfloat4)(0.f);

    if (t == 0) {
        val = *reinterpret_cast<const vfloat4*>(CLS + doff);
    } else if (t <= lxb) {
        const float* src = X + ((size_t)(b * LX_ + (t - 1)) * D_ + doff);
        val = __builtin_nontemporal_load(reinterpret_cast<const vfloat4*>(src));
    } else if (t == lxb + 1) {
        val = *reinterpret_cast<const vfloat4*>(RING + doff);
    } else if (t < lxb + 2 + lrb) {
        const float* src = Xr + ((size_t)(b * LR_ + (t - lxb - 2)) * D_ + doff);
        val = __builtin_nontemporal_load(reinterpret_cast<const vfloat4*>(src));
    } else if (t == lxb + lrb + 2) {
        val = *reinterpret_cast<const vfloat4*>(END + doff);
    }

    __builtin_nontemporal_store(val,
        reinterpret_cast<vfloat4*>(out + (size_t)row * D_ + doff));
}

extern "C" void kernel_launch(void* const* d_in, const int* in_sizes, int n_in,
                              void* d_out, int out_size, void* d_ws, size_t ws_size,
                              hipStream_t stream)
{
    const float* X    = (const float*)d_in[0];
    const float* Xr   = (const float*)d_in[1];
    const float* CLS  = (const float*)d_in[2];
    const float* RING = (const float*)d_in[3];
    const float* END  = (const float*)d_in[4];
    const int* lx = (const int*)d_in[5];
    const int* lr = (const int*)d_in[6];
    float* out = (float*)d_out;

    hipLaunchKernelGGL(assemble_row_kernel, dim3(NROW), dim3(192), 0, stream,
                       X, Xr, CLS, RING, END, lx, lr, out);
}